// Round 1
// baseline (119.550 us; speedup 1.0000x reference)
//
#include <hip/hip_runtime.h>

#define DEG 32
#define HID 32
#define CIN 8

typedef float v2f __attribute__((ext_vector_type(2)));
typedef short bf16x8 __attribute__((ext_vector_type(8)));   // 8 bf16 = 4 VGPRs
typedef float f32x16 __attribute__((ext_vector_type(16)));  // MFMA 32x32 C/D

// gelu(t) = t * rcp(1 + exp2(-t*(A + B*t^2)))   [jax tanh-approx, sigmoid form]
#define GELU_A ((float)(2.0 * 1.4426950408889634 * 0.7978845608028654))
#define GELU_B ((float)(2.0 * 1.4426950408889634 * 0.7978845608028654 * 0.044715))

__device__ __forceinline__ unsigned f2bf(float f) {   // fp32 -> bf16 (RNE)
    unsigned b = __float_as_uint(f);
    return (b + 0x7fffu + ((b >> 16) & 1u)) >> 16;
}
__device__ __forceinline__ unsigned pack2(float lo, float hi) {
    return f2bf(lo) | (f2bf(hi) << 16);
}

// Phase 1: x16[n] = bf16(x[n]) (16 B row -> 1.6 MB gather table, L2-resident);
// w1f / w2f = W1 / W2 in MFMA B-fragment order (frag f: lane l holds
// B[k = f*16 + (l>>5)*8 + j][col = l&31], j=0..7).
__global__ __launch_bounds__(256) void precompute_xw(
    const float* __restrict__ x, const float* __restrict__ W1,
    const float* __restrict__ W2, unsigned* __restrict__ x16,
    unsigned* __restrict__ w1f, unsigned* __restrict__ w2f, int N) {
    int tid = blockIdx.x * 256 + threadIdx.x;
    if (blockIdx.x == 0) {
        int t = threadIdx.x;
        if (t < 64) {                       // W1 fragment (K=16 exactly)
            int kb = (t >> 5) * 8, col = t & 31;
            uint4 o;
            o.x = pack2(W1[(kb + 0) * HID + col], W1[(kb + 1) * HID + col]);
            o.y = pack2(W1[(kb + 2) * HID + col], W1[(kb + 3) * HID + col]);
            o.z = pack2(W1[(kb + 4) * HID + col], W1[(kb + 5) * HID + col]);
            o.w = pack2(W1[(kb + 6) * HID + col], W1[(kb + 7) * HID + col]);
            *(uint4*)(w1f + t * 4) = o;
        } else if (t < 192) {               // W2 fragments (K=32 -> 2 frags)
            int u = t - 64;
            int f = u >> 6, l = u & 63;
            int kb = f * 16 + ((l >> 5) * 8), col = l & 31;
            uint4 o;
            o.x = pack2(W2[(kb + 0) * HID + col], W2[(kb + 1) * HID + col]);
            o.y = pack2(W2[(kb + 2) * HID + col], W2[(kb + 3) * HID + col]);
            o.z = pack2(W2[(kb + 4) * HID + col], W2[(kb + 5) * HID + col]);
            o.w = pack2(W2[(kb + 6) * HID + col], W2[(kb + 7) * HID + col]);
            *(uint4*)(w2f + (f * 64 + l) * 4) = o;
        }
    }
    if (tid < N) {
        const float4* xp = (const float4*)(x + (size_t)tid * CIN);
        float4 a = xp[0], b = xp[1];
        uint4 o;
        o.x = pack2(a.x, a.y);  o.y = pack2(a.z, a.w);
        o.z = pack2(b.x, b.y);  o.w = pack2(b.z, b.w);
        *(uint4*)(x16 + (size_t)tid * 4) = o;
    }
}

// gelu (with bias) + edge-weighted row-sum over one node's C fragment.
// C-layout: col=lane&31 (=hid), row(i) = (i&3) + 8*(i>>2) + 4*(lane>>5).
// Weights consumed quad-at-a-time to keep live registers low.
__device__ __forceinline__ float gelu_reduce(const f32x16& acc, const float* swp,
                                             float b1v) {
    v2f gacc = {0.f, 0.f};
#pragma unroll
    for (int q = 0; q < 4; ++q) {
        float4 wq = *(const float4*)(swp + 8 * q);   // rows 8q+4hi .. +3 (broadcast)
#pragma unroll
        for (int h = 0; h < 2; ++h) {
            int i = q * 4 + h * 2;
            v2f tt = {acc[i] + b1v, acc[i + 1] + b1v};
            v2f x2 = tt * tt;
            v2f zz = tt * (x2 * (-GELU_B) + (-GELU_A));
            v2f ee;
            ee.x = __builtin_amdgcn_exp2f(zz.x);  ee.y = __builtin_amdgcn_exp2f(zz.y);
            v2f dd = ee + 1.0f;
            v2f rr;
            rr.x = __builtin_amdgcn_rcpf(dd.x);   rr.y = __builtin_amdgcn_rcpf(dd.y);
            v2f wp = h ? (v2f){wq.z, wq.w} : (v2f){wq.x, wq.y};
            gacc += wp * (tt * rr);                  // gelu = t*sigmoid; exact limits
        }
    }
    float g = gacc.x + gacc.y;
    g += __shfl_xor(g, 32);                      // combine the two row-halves
    return g;
}

// Persistent fused main: 2048 grid-stride blocks, 256 thr = 4 waves = 8 nodes
// per group.  Depth-2 software pipeline per wave:
//   iter(g): issue wgt/x16 gathers for g+1 (nbr row already in flight since
//            g-1), issue nbr row for g+2, then compute group g.
// Both of a wave's nodes share one nbr load / one wgt gather (low half =
// node0 edges, high half = node1 edges); node1's edge list is recovered into
// low lanes with one __shfl_xor(...,32).  sg/sws double-buffered -> single
// barrier per iteration; epilogue rotates across waves (wv == g&3).
__global__ __launch_bounds__(256) void git_fused(
    const unsigned* __restrict__ x16, const unsigned* __restrict__ w1f,
    const unsigned* __restrict__ w2f, const float* __restrict__ wgt,
    const float* __restrict__ b1, const float* __restrict__ b2,
    const int* __restrict__ nbr, float* __restrict__ out, int N) {
    __shared__ float sw[8 * DEG];                       // per-node edge weights
                                                        // (only owner wave touches
                                                        //  its rows -> no dbuf)
    __shared__ __align__(16) unsigned short sg[2][32 * 40];  // g rows, stride 40 u16
    __shared__ __align__(16) float          sws[2][8];       // per-node weight sums

    const int ngroups = (N + 7) >> 3;
    int t = threadIdx.x;
    int wv = t >> 6;                   // wave 0..3
    int l  = t & 63;
    int l5 = l & 31;
    int hi = l >> 5;

    // hoisted per-session constants (amortized over ~6 groups)
    bf16x8 bfrag = *((const bf16x8*)w1f + l);        // shared W1 fragment
    bf16x8 eb1   = *((const bf16x8*)w2f + l);        // W2 frag k 0-15
    bf16x8 eb2   = *((const bf16x8*)w2f + 64 + l);   // W2 frag k 16-31
    float  myb1  = b1[l5];
    float  myb2  = b2[l5];
    const bf16x8* x16v = (const bf16x8*)x16;

    int g = blockIdx.x;
    const int gstep = gridDim.x;
    if (g >= ngroups) return;

    // ---- prologue: state for group g, then nbr row for g+gstep ----
    int nb0 = g * 8 + wv * 2;
    int n0c = min(nb0, N - 1), n1c = min(nb0 + 1, N - 1);
    int   J = nbr[(hi ? n1c : n0c) * DEG + l5];      // lo: node0 edges, hi: node1
    float W = wgt[J];
    int jsw = __shfl_xor(J, 32);
    bf16x8 A0 = x16v[hi ? n0c : J];                  // lanes 0-31 x_j, 32-63 x_i
    bf16x8 A1 = x16v[hi ? n1c : jsw];

    int gn = g + gstep;
    int Jn = 0;
    if (gn < ngroups) {
        int nbn = gn * 8 + wv * 2;
        Jn = nbr[min(nbn + hi, N - 1) * DEG + l5];
    }

    int p = 0;
    while (true) {
        // ---- issue group g+1 gathers (Jn in flight for a full iteration) and
        //      group g+2's nbr row ----
        bf16x8 A0n, A1n;
        float  Wn = 0.f;
        int gn2 = gn + gstep;
        int Jn2 = 0;
        if (gn < ngroups) {
            int nbn = gn * 8 + wv * 2;
            int n0n = min(nbn, N - 1), n1n = min(nbn + 1, N - 1);
            Wn = wgt[Jn];
            int jswn = __shfl_xor(Jn, 32);
            A0n = x16v[hi ? n0n : Jn];
            A1n = x16v[hi ? n1n : jswn];
            if (gn2 < ngroups) {
                Jn2 = nbr[min(gn2 * 8 + wv * 2 + hi, N - 1) * DEG + l5];
            }
        }

        // ---- compute current group g ----
        float ws = W;                                // per-half butterfly sum
        ws += __shfl_xor(ws, 1);  ws += __shfl_xor(ws, 2);
        ws += __shfl_xor(ws, 4);  ws += __shfl_xor(ws, 8);
        ws += __shfl_xor(ws, 16);
        sw[(wv * 2 + hi) * DEG + l5] = W;
        if (l5 == 0) sws[p][wv * 2 + hi] = ws;

        f32x16 z0 = {}, z1 = {};
        f32x16 a0 = __builtin_amdgcn_mfma_f32_32x32x16_bf16(A0, bfrag, z0, 0, 0, 0);
        f32x16 a1 = __builtin_amdgcn_mfma_f32_32x32x16_bf16(A1, bfrag, z1, 0, 0, 0);

        const float* swb = &sw[wv * 2 * DEG + hi * 4];
        float g0 = gelu_reduce(a0, swb, myb1);
        float g1 = gelu_reduce(a1, swb + DEG, myb1);

        if (hi == 0) {
            sg[p][(wv * 2 + 0) * 40 + l5] = (unsigned short)f2bf(g0);
            sg[p][(wv * 2 + 1) * 40 + l5] = (unsigned short)f2bf(g1);
        }

        __syncthreads();                   // all 8 g rows + ws of buffer p staged

        // ---- epilogue (rotating wave): out = (G @ W2 + ws x b2)/32, 8 nodes ----
        if (wv == (g & 3)) {
            // A rows 0..7 valid; rows 8..31 read stale LDS (their D rows unused).
            const char* sgb = (const char*)sg[p];
            bf16x8 ea1 = *(const bf16x8*)(sgb + l5 * 80 + hi * 16);        // k 0-15
            bf16x8 ea2 = *(const bf16x8*)(sgb + l5 * 80 + 32 + hi * 16);   // k 16-31
            f32x16 zz = {};
            f32x16 acc = __builtin_amdgcn_mfma_f32_32x32x16_bf16(ea1, eb1, zz, 0, 0, 0);
            acc = __builtin_amdgcn_mfma_f32_32x32x16_bf16(ea2, eb2, acc, 0, 0, 0);

            float4 wsq = *(const float4*)(&sws[p][hi * 4]);   // rows hi*4 .. +3
            float wsa[4] = {wsq.x, wsq.y, wsq.z, wsq.w};
            // stored rows: i=0..3 -> r=i+4*hi (i>=4 map to r>=8: unused)
#pragma unroll
            for (int i = 0; i < 4; ++i) {
                int r = i + 4 * hi;
                int node = g * 8 + r;
                if (node < N)
                    out[(size_t)node * HID + l5] =
                        fmaf(wsa[i], myb2, acc[i]) * (1.0f / DEG);
            }
        }

        if (gn >= ngroups) break;
        // ---- rotate pipeline state ----
        g = gn;  gn = gn2;
        J = Jn;  Jn = Jn2;
        W = Wn;  A0 = A0n;  A1 = A1n;
        p ^= 1;
    }
}

// Fallback if d_ws too small: single fused kernel (no workspace tables).
__global__ __launch_bounds__(256) void fused_fallback(
    const float* __restrict__ x, const float* __restrict__ wgt,
    const float* __restrict__ W1, const float* __restrict__ b1,
    const float* __restrict__ W2, const float* __restrict__ b2,
    const int* __restrict__ nbr, float* __restrict__ out, int N) {
    __shared__ float sW2[HID * HID];
    __shared__ float sb2[HID];
    __shared__ int2  sp[8 * DEG];
    int t = threadIdx.x;
#pragma unroll
    for (int i = 0; i < 4; ++i) sW2[t + i * 256] = W2[t + i * 256];
    if (t < HID) sb2[t] = b2[t];
    int slot = t >> 5, hid = t & 31;
    int node = blockIdx.x * 8 + slot;
    bool valid = node < N;
    int nc = valid ? node : (N - 1);
    int   j_own = nbr[nc * DEG + hid];
    float w_own = wgt[j_own];
    sp[slot * DEG + hid] = make_int2(j_own * (CIN * 4), __float_as_int(w_own));
    const float4* xip = (const float4*)(x + (size_t)nc * CIN);
    float4 xa = xip[0], xb = xip[1];
    float w1t[8];
#pragma unroll
    for (int k = 0; k < 8; ++k) w1t[k] = W1[k * HID + hid];
    float vb = b1[hid];
    vb = fmaf(xa.x, W1[ 8 * HID + hid], vb);
    vb = fmaf(xa.y, W1[ 9 * HID + hid], vb);
    vb = fmaf(xa.z, W1[10 * HID + hid], vb);
    vb = fmaf(xa.w, W1[11 * HID + hid], vb);
    vb = fmaf(xb.x, W1[12 * HID + hid], vb);
    vb = fmaf(xb.y, W1[13 * HID + hid], vb);
    vb = fmaf(xb.z, W1[14 * HID + hid], vb);
    vb = fmaf(xb.w, W1[15 * HID + hid], vb);
    float ws = w_own;
    ws += __shfl_xor(ws, 1);  ws += __shfl_xor(ws, 2);
    ws += __shfl_xor(ws, 4);  ws += __shfl_xor(ws, 8);
    ws += __shfl_xor(ws, 16);
    __syncthreads();
    const char* xbytes = (const char*)x;
    const int2* myp = &sp[slot * DEG];
    float g = 0.f;
#pragma unroll 8
    for (int e = 0; e < DEG; ++e) {
        int2  p  = myp[e];
        float wjv = __int_as_float(p.y);
        const float4* xjp = (const float4*)(xbytes + (unsigned)p.x);
        float4 a = xjp[0], b = xjp[1];
        float tin = vb;
        tin = fmaf(a.x, w1t[0], tin); tin = fmaf(a.y, w1t[1], tin);
        tin = fmaf(a.z, w1t[2], tin); tin = fmaf(a.w, w1t[3], tin);
        tin = fmaf(b.x, w1t[4], tin); tin = fmaf(b.y, w1t[5], tin);
        tin = fmaf(b.z, w1t[6], tin); tin = fmaf(b.w, w1t[7], tin);
        float x2 = tin * tin;
        float z  = tin * fmaf(GELU_B, x2, GELU_A);
        float e2 = __builtin_amdgcn_exp2f(z);
        float r  = __builtin_amdgcn_rcpf(1.0f + e2);
        g = fmaf(wjv, fmaf(-tin, r, tin), g);
    }
    float acc = 0.f;
#pragma unroll
    for (int h = 0; h < HID; ++h) {
        float gh = __shfl(g, h, 32);
        acc = fmaf(gh, sW2[h * HID + hid], acc);
    }
    if (valid) out[(size_t)node * HID + hid] = fmaf(ws, sb2[hid], acc) * (1.0f / DEG);
}

extern "C" void kernel_launch(void* const* d_in, const int* in_sizes, int n_in,
                              void* d_out, int out_size, void* d_ws, size_t ws_size,
                              hipStream_t stream) {
    const float* x   = (const float*)d_in[0];
    const float* wq  = (const float*)d_in[1];
    const float* W1  = (const float*)d_in[2];
    const float* b1  = (const float*)d_in[3];
    const float* W2  = (const float*)d_in[4];
    const float* b2  = (const float*)d_in[5];
    const int*   nbr = (const int*)d_in[6];
    float* out = (float*)d_out;

    int N = in_sizes[1];                        // in_weights has N elements

    size_t off_x16 = 0;
    size_t off_w1  = (off_x16 + (size_t)N * 16 + 255) & ~(size_t)255;
    size_t off_w2  = off_w1 + 1024;
    size_t need    = off_w2 + 2048;

    if (ws_size >= need) {
        unsigned* x16 = (unsigned*)((char*)d_ws + off_x16);
        unsigned* w1f = (unsigned*)((char*)d_ws + off_w1);
        unsigned* w2f = (unsigned*)((char*)d_ws + off_w2);

        int blocks_pre = (N + 255) / 256;
        precompute_xw<<<blocks_pre, 256, 0, stream>>>(x, W1, W2, x16, w1f, w2f, N);

        int ngroups = (N + 7) / 8;
        int blocks_main = ngroups < 2048 ? ngroups : 2048;  // 8 blocks/CU persistent
        git_fused<<<blocks_main, 256, 0, stream>>>(x16, w1f, w2f, wq, b1, b2,
                                                   nbr, out, N);
    } else {
        int blocks = (N + 7) / 8;
        fused_fallback<<<blocks, 256, 0, stream>>>(x, wq, W1, b1, W2, b2, nbr, out, N);
    }
}

// Round 2
// 115.770 us; speedup vs baseline: 1.0327x; 1.0327x over previous
//
#include <hip/hip_runtime.h>

#define DEG 32
#define HID 32
#define CIN 8

typedef float v2f __attribute__((ext_vector_type(2)));
typedef short bf16x8 __attribute__((ext_vector_type(8)));   // 8 bf16 = 4 VGPRs
typedef float f32x16 __attribute__((ext_vector_type(16)));  // MFMA 32x32 C/D

// gelu(t) = t * rcp(1 + exp2(-t*(A + B*t^2)))   [jax tanh-approx, sigmoid form]
#define GELU_A ((float)(2.0 * 1.4426950408889634 * 0.7978845608028654))
#define GELU_B ((float)(2.0 * 1.4426950408889634 * 0.7978845608028654 * 0.044715))

__device__ __forceinline__ unsigned f2bf(float f) {   // fp32 -> bf16 (RNE)
    unsigned b = __float_as_uint(f);
    return (b + 0x7fffu + ((b >> 16) & 1u)) >> 16;
}
__device__ __forceinline__ unsigned pack2(float lo, float hi) {
    return f2bf(lo) | (f2bf(hi) << 16);
}

// Phase 1: x16[n] = bf16(x[n]) (16 B row -> 1.6 MB gather table, L2-resident);
// w1f / w2f = W1 / W2 in MFMA B-fragment order (frag f: lane l holds
// B[k = f*16 + (l>>5)*8 + j][col = l&31], j=0..7).
__global__ __launch_bounds__(256) void precompute_xw(
    const float* __restrict__ x, const float* __restrict__ W1,
    const float* __restrict__ W2, unsigned* __restrict__ x16,
    unsigned* __restrict__ w1f, unsigned* __restrict__ w2f, int N) {
    int tid = blockIdx.x * 256 + threadIdx.x;
    if (blockIdx.x == 0) {
        int t = threadIdx.x;
        if (t < 64) {                       // W1 fragment (K=16 exactly)
            int kb = (t >> 5) * 8, col = t & 31;
            uint4 o;
            o.x = pack2(W1[(kb + 0) * HID + col], W1[(kb + 1) * HID + col]);
            o.y = pack2(W1[(kb + 2) * HID + col], W1[(kb + 3) * HID + col]);
            o.z = pack2(W1[(kb + 4) * HID + col], W1[(kb + 5) * HID + col]);
            o.w = pack2(W1[(kb + 6) * HID + col], W1[(kb + 7) * HID + col]);
            *(uint4*)(w1f + t * 4) = o;
        } else if (t < 192) {               // W2 fragments (K=32 -> 2 frags)
            int u = t - 64;
            int f = u >> 6, l = u & 63;
            int kb = f * 16 + ((l >> 5) * 8), col = l & 31;
            uint4 o;
            o.x = pack2(W2[(kb + 0) * HID + col], W2[(kb + 1) * HID + col]);
            o.y = pack2(W2[(kb + 2) * HID + col], W2[(kb + 3) * HID + col]);
            o.z = pack2(W2[(kb + 4) * HID + col], W2[(kb + 5) * HID + col]);
            o.w = pack2(W2[(kb + 6) * HID + col], W2[(kb + 7) * HID + col]);
            *(uint4*)(w2f + (f * 64 + l) * 4) = o;
        }
    }
    if (tid < N) {
        const float4* xp = (const float4*)(x + (size_t)tid * CIN);
        float4 a = xp[0], b = xp[1];
        uint4 o;
        o.x = pack2(a.x, a.y);  o.y = pack2(a.z, a.w);
        o.z = pack2(b.x, b.y);  o.w = pack2(b.z, b.w);
        *(uint4*)(x16 + (size_t)tid * 4) = o;
    }
}

// gelu (with bias) + edge-weighted row-sum over one node's C fragment.
// C-layout: col=lane&31 (=hid), row(i) = (i&3) + 8*(i>>2) + 4*(lane>>5).
// Weights consumed quad-at-a-time (LDS float4 broadcast per half).
__device__ __forceinline__ float gelu_reduce(const f32x16& acc, const float* swp,
                                             float b1v) {
    v2f gacc = {0.f, 0.f};
#pragma unroll
    for (int q = 0; q < 4; ++q) {
        float4 wq = *(const float4*)(swp + 8 * q);   // rows 8q+4hi .. +3 (broadcast)
#pragma unroll
        for (int h = 0; h < 2; ++h) {
            int i = q * 4 + h * 2;
            v2f tt = {acc[i] + b1v, acc[i + 1] + b1v};
            v2f x2 = tt * tt;
            v2f zz = tt * (x2 * (-GELU_B) + (-GELU_A));
            v2f ee;
            ee.x = __builtin_amdgcn_exp2f(zz.x);  ee.y = __builtin_amdgcn_exp2f(zz.y);
            v2f dd = ee + 1.0f;
            v2f rr;
            rr.x = __builtin_amdgcn_rcpf(dd.x);   rr.y = __builtin_amdgcn_rcpf(dd.y);
            v2f wp = h ? (v2f){wq.z, wq.w} : (v2f){wq.x, wq.y};
            gacc += wp * (tt * rr);                  // gelu = t*sigmoid; exact limits
        }
    }
    float g = gacc.x + gacc.y;
    g += __shfl_xor(g, 32);                      // combine the two row-halves
    return g;
}

// Fused main: 256-thr block = 4 FULLY INDEPENDENT waves, 4 nodes/wave
// (16 nodes/block).  ZERO barriers: each wave stages its own g rows in a
// private LDS strip (same-wave write->read, lgkmcnt only) and runs its own
// W2 epilogue.  nbr/wgt gathers dedup'd: one load covers 2 nodes (lo half =
// node0 edges, hi half = node1), recovered via __shfl_xor(...,32).
// 8 gathers in flight per wave amortize the ~500-900 cyc gather chain.
__global__ __launch_bounds__(256, 4) void git_fused(
    const unsigned* __restrict__ x16, const unsigned* __restrict__ w1f,
    const unsigned* __restrict__ w2f, const float* __restrict__ wgt,
    const float* __restrict__ b1, const float* __restrict__ b2,
    const int* __restrict__ nbr, float* __restrict__ out, int N) {
    __shared__ float sw[4 * 4 * 32];    // [wave][node 0..3][edge] weights
    // per-wave g strip: 4 rows x stride 40 u16 (80 B, 16B-aligned rows).
    // Epilogue A-reads touch rows 0..31 from each wave base (rows 4+ are
    // don't-care garbage) -> size covers wv*160 + 32*40 + slack.
    __shared__ __align__(16) unsigned short sg[1792];

    int t = threadIdx.x;
    int wv = t >> 6;                   // wave 0..3
    int l  = t & 63;
    int l5 = l & 31;
    int hi = l >> 5;
    int nb = blockIdx.x * 16 + wv * 4; // this wave's 4 nodes

    int n0 = min(nb + 0, N - 1), n1 = min(nb + 1, N - 1);
    int n2 = min(nb + 2, N - 1), n3 = min(nb + 3, N - 1);

    // ---- dedup'd index/weight gathers: 2 loads cover 4 nodes ----
    int JA = nbr[(hi ? n1 : n0) * DEG + l5];       // lo: node0, hi: node1
    int JB = nbr[(hi ? n3 : n2) * DEG + l5];       // lo: node2, hi: node3
    float WA = wgt[JA];
    float WB = wgt[JB];
    int jswA = __shfl_xor(JA, 32);                 // lo lanes get node1's edges
    int jswB = __shfl_xor(JB, 32);                 // lo lanes get node3's edges

    // ---- A-fragment gathers (all 4 in flight): lo = x_j, hi = x_i ----
    const bf16x8* x16v = (const bf16x8*)x16;
    bf16x8 A0 = x16v[hi ? n0 : JA];
    bf16x8 A1 = x16v[hi ? n1 : jswA];
    bf16x8 A2 = x16v[hi ? n2 : JB];
    bf16x8 A3 = x16v[hi ? n3 : jswB];
    bf16x8 bfrag = *((const bf16x8*)w1f + l);      // shared W1 fragment
    bf16x8 eb1   = *((const bf16x8*)w2f + l);      // W2 frag k 0-15
    bf16x8 eb2   = *((const bf16x8*)w2f + 64 + l); // W2 frag k 16-31
    float myb1 = b1[l5];
    float myb2 = b2[l5];

    // stage edge weights for gelu_reduce broadcast reads (own wave only)
    float* swv = &sw[wv * 128];
    swv[hi * 32 + l5]      = WA;
    swv[64 + hi * 32 + l5] = WB;

    // per-half butterfly weight sums: lo half = even node, hi half = odd node
    float wsA = WA, wsB = WB;
    wsA += __shfl_xor(wsA, 1);  wsA += __shfl_xor(wsA, 2);
    wsA += __shfl_xor(wsA, 4);  wsA += __shfl_xor(wsA, 8);
    wsA += __shfl_xor(wsA, 16);
    wsB += __shfl_xor(wsB, 1);  wsB += __shfl_xor(wsB, 2);
    wsB += __shfl_xor(wsB, 4);  wsB += __shfl_xor(wsB, 8);
    wsB += __shfl_xor(wsB, 16);

    // ---- W1 MFMAs + gelu/weighted-reduce (pairwise to cap acc liveness) ----
    f32x16 z0 = {}, z1 = {};
    f32x16 a0 = __builtin_amdgcn_mfma_f32_32x32x16_bf16(A0, bfrag, z0, 0, 0, 0);
    f32x16 a1 = __builtin_amdgcn_mfma_f32_32x32x16_bf16(A1, bfrag, z1, 0, 0, 0);
    float g0 = gelu_reduce(a0, swv + hi * 4,      myb1);
    float g1 = gelu_reduce(a1, swv + 32 + hi * 4, myb1);
    f32x16 z2 = {}, z3 = {};
    f32x16 a2 = __builtin_amdgcn_mfma_f32_32x32x16_bf16(A2, bfrag, z2, 0, 0, 0);
    f32x16 a3 = __builtin_amdgcn_mfma_f32_32x32x16_bf16(A3, bfrag, z3, 0, 0, 0);
    float g2 = gelu_reduce(a2, swv + 64 + hi * 4, myb1);
    float g3 = gelu_reduce(a3, swv + 96 + hi * 4, myb1);

    // ---- stage g rows (both halves hold all 4 values; split the writes) ----
    unsigned short* sgw = &sg[wv * 160];           // 4 rows x 40 u16
    float ga = hi ? g2 : g0;
    float gb = hi ? g3 : g1;
    sgw[(2 * hi + 0) * 40 + l5] = (unsigned short)f2bf(ga);
    sgw[(2 * hi + 1) * 40 + l5] = (unsigned short)f2bf(gb);

    // ws broadcast to all lanes (needed per output row)
    float wsa[4];
    wsa[0] = __shfl(wsA, 0);
    wsa[1] = __shfl(wsA, 32);
    wsa[2] = __shfl(wsB, 0);
    wsa[3] = __shfl(wsB, 32);

    // ---- per-wave epilogue: out = (G @ W2 + ws x b2)/32 for 4 nodes ----
    // A rows 0..3 valid; rows 4..31 read don't-care LDS (their D rows unused).
    const char* sgb = (const char*)sgw;
    bf16x8 ea1 = *(const bf16x8*)(sgb + l5 * 80 + hi * 16);        // k 0-15
    bf16x8 ea2 = *(const bf16x8*)(sgb + l5 * 80 + 32 + hi * 16);   // k 16-31
    f32x16 zz = {};
    f32x16 acc = __builtin_amdgcn_mfma_f32_32x32x16_bf16(ea1, eb1, zz, 0, 0, 0);
    acc = __builtin_amdgcn_mfma_f32_32x32x16_bf16(ea2, eb2, acc, 0, 0, 0);

    // stored rows: i=0..3 -> r=i+4*hi; only hi==0 rows are our nodes
    if (hi == 0) {
#pragma unroll
        for (int i = 0; i < 4; ++i) {
            int node = nb + i;
            if (node < N)
                out[(size_t)node * HID + l5] =
                    fmaf(wsa[i], myb2, acc[i]) * (1.0f / DEG);
        }
    }
}

// Fallback if d_ws too small: single fused kernel (no workspace tables).
__global__ __launch_bounds__(256) void fused_fallback(
    const float* __restrict__ x, const float* __restrict__ wgt,
    const float* __restrict__ W1, const float* __restrict__ b1,
    const float* __restrict__ W2, const float* __restrict__ b2,
    const int* __restrict__ nbr, float* __restrict__ out, int N) {
    __shared__ float sW2[HID * HID];
    __shared__ float sb2[HID];
    __shared__ int2  sp[8 * DEG];
    int t = threadIdx.x;
#pragma unroll
    for (int i = 0; i < 4; ++i) sW2[t + i * 256] = W2[t + i * 256];
    if (t < HID) sb2[t] = b2[t];
    int slot = t >> 5, hid = t & 31;
    int node = blockIdx.x * 8 + slot;
    bool valid = node < N;
    int nc = valid ? node : (N - 1);
    int   j_own = nbr[nc * DEG + hid];
    float w_own = wgt[j_own];
    sp[slot * DEG + hid] = make_int2(j_own * (CIN * 4), __float_as_int(w_own));
    const float4* xip = (const float4*)(x + (size_t)nc * CIN);
    float4 xa = xip[0], xb = xip[1];
    float w1t[8];
#pragma unroll
    for (int k = 0; k < 8; ++k) w1t[k] = W1[k * HID + hid];
    float vb = b1[hid];
    vb = fmaf(xa.x, W1[ 8 * HID + hid], vb);
    vb = fmaf(xa.y, W1[ 9 * HID + hid], vb);
    vb = fmaf(xa.z, W1[10 * HID + hid], vb);
    vb = fmaf(xa.w, W1[11 * HID + hid], vb);
    vb = fmaf(xb.x, W1[12 * HID + hid], vb);
    vb = fmaf(xb.y, W1[13 * HID + hid], vb);
    vb = fmaf(xb.z, W1[14 * HID + hid], vb);
    vb = fmaf(xb.w, W1[15 * HID + hid], vb);
    float ws = w_own;
    ws += __shfl_xor(ws, 1);  ws += __shfl_xor(ws, 2);
    ws += __shfl_xor(ws, 4);  ws += __shfl_xor(ws, 8);
    ws += __shfl_xor(ws, 16);
    __syncthreads();
    const char* xbytes = (const char*)x;
    const int2* myp = &sp[slot * DEG];
    float g = 0.f;
#pragma unroll 8
    for (int e = 0; e < DEG; ++e) {
        int2  p  = myp[e];
        float wjv = __int_as_float(p.y);
        const float4* xjp = (const float4*)(xbytes + (unsigned)p.x);
        float4 a = xjp[0], b = xjp[1];
        float tin = vb;
        tin = fmaf(a.x, w1t[0], tin); tin = fmaf(a.y, w1t[1], tin);
        tin = fmaf(a.z, w1t[2], tin); tin = fmaf(a.w, w1t[3], tin);
        tin = fmaf(b.x, w1t[4], tin); tin = fmaf(b.y, w1t[5], tin);
        tin = fmaf(b.z, w1t[6], tin); tin = fmaf(b.w, w1t[7], tin);
        float x2 = tin * tin;
        float z  = tin * fmaf(GELU_B, x2, GELU_A);
        float e2 = __builtin_amdgcn_exp2f(z);
        float r  = __builtin_amdgcn_rcpf(1.0f + e2);
        g = fmaf(wjv, fmaf(-tin, r, tin), g);
    }
    float acc = 0.f;
#pragma unroll
    for (int h = 0; h < HID; ++h) {
        float gh = __shfl(g, h, 32);
        acc = fmaf(gh, sW2[h * HID + hid], acc);
    }
    if (valid) out[(size_t)node * HID + hid] = fmaf(ws, sb2[hid], acc) * (1.0f / DEG);
}

extern "C" void kernel_launch(void* const* d_in, const int* in_sizes, int n_in,
                              void* d_out, int out_size, void* d_ws, size_t ws_size,
                              hipStream_t stream) {
    const float* x   = (const float*)d_in[0];
    const float* wq  = (const float*)d_in[1];
    const float* W1  = (const float*)d_in[2];
    const float* b1  = (const float*)d_in[3];
    const float* W2  = (const float*)d_in[4];
    const float* b2  = (const float*)d_in[5];
    const int*   nbr = (const int*)d_in[6];
    float* out = (float*)d_out;

    int N = in_sizes[1];                        // in_weights has N elements

    size_t off_x16 = 0;
    size_t off_w1  = (off_x16 + (size_t)N * 16 + 255) & ~(size_t)255;
    size_t off_w2  = off_w1 + 1024;
    size_t need    = off_w2 + 2048;

    if (ws_size >= need) {
        unsigned* x16 = (unsigned*)((char*)d_ws + off_x16);
        unsigned* w1f = (unsigned*)((char*)d_ws + off_w1);
        unsigned* w2f = (unsigned*)((char*)d_ws + off_w2);

        int blocks_pre = (N + 255) / 256;
        precompute_xw<<<blocks_pre, 256, 0, stream>>>(x, W1, W2, x16, w1f, w2f, N);

        int blocks_main = (N + 15) / 16;        // 16 nodes per 256-thread block
        git_fused<<<blocks_main, 256, 0, stream>>>(x16, w1f, w2f, wq, b1, b2,
                                                   nbr, out, N);
    } else {
        int blocks = (N + 7) / 8;
        fused_fallback<<<blocks, 256, 0, stream>>>(x, wq, W1, b1, W2, b2, nbr, out, N);
    }
}